// Round 2
// baseline (61.776 us; speedup 1.0000x reference)
//
#include <hip/hip_runtime.h>
#include <math.h>

// PathRaster2d: quadratic Bezier (3 ctrl pts), 32 uniform-t samples,
// canvas 2048x2048 fp32. out = (dist<2) ? 1 - dist/sqrt(H^2+W^2) : 0.
//
// Numerics mirror the numpy fp32 reference op-for-op (see R1: absmax=0):
//  - t_i = float( double(i) * (1.0/31.0) ), t_31 = 1.0  (np.linspace)
//  - basis: (1-t)*(1-t), (2t)*(1-t), t*t
//  - samples: ((b0*k0 + b1*k1) + b2*k2), unfused (fp contract off)
//  - dist2:  dy*dy + dx*dx, unfused; min over samples; IEEE sqrt; IEEE div.
// Any fused/reordered variant risks a 1-ulp flip of the dist<2 predicate
// (unit discontinuity -> absmax 1.0).
//
// R2 change: 64x64-px tiles (1024 blocks instead of 4096), 4x float4 stores
// per thread — shrink dispatch ramp; store path otherwise identical.

#define NSAMP 32
#define CANVAS_W 2048

__global__ __launch_bounds__(256) void PathRaster2d_kernel(
    const float* __restrict__ kp, float* __restrict__ out) {
#pragma clang fp contract(off)
    __shared__ float s_y[NSAMP];
    __shared__ float s_x[NSAMP];

    const int tid = threadIdx.x;

    // Tile = 64x64 pixels. Center for the cull test.
    const float cy = (float)(blockIdx.y * 64) + 31.5f;
    const float cx = (float)(blockIdx.x * 64) + 31.5f;

    int pred = 0;
    if (tid < NSAMP) {
        // np.linspace(0,1,32): step = 1/31 in f64, y_i = i*step, endpoint exact.
        double td = (tid == NSAMP - 1) ? 1.0 : (double)tid * (1.0 / 31.0);
        float t = (float)td;
        float u = 1.0f - t;
        float b0 = u * u;            // comb(2,0) * (1-t)^2
        float b1 = (2.0f * t) * u;   // comb(2,1)*t, then *(1-t)
        float b2 = t * t;            // comb(2,2) * t^2
        float ky0 = kp[0] * 2048.0f, kx0 = kp[1] * 2048.0f;
        float ky1 = kp[2] * 2048.0f, kx1 = kp[3] * 2048.0f;
        float ky2 = kp[4] * 2048.0f, kx2 = kp[5] * 2048.0f;
        // basis @ kp, sequential left-to-right, no fma (contract off).
        float sy = (b0 * ky0 + b1 * ky1) + b2 * ky2;
        float sx = (b0 * kx0 + b1 * kx1) + b2 * kx2;
        s_y[tid] = sy;
        s_x[tid] = sx;
        // Cull: sample within (2 + 31.5*sqrt2 ~= 46.6) of tile center.
        // Conservative threshold 48^2 = 2304 absorbs all fp32 slop.
        float dyc = cy - sy;
        float dxc = cx - sx;
        pred = (dyc * dyc + dxc * dxc) < 2304.0f;
    }
    int any_near = __syncthreads_or(pred);  // barrier + OR; s_y/s_x visible

    // Thread -> 16 pixels: rows r, r+16, r+32, r+48; cols c4..c4+3.
    const int r  = tid >> 4;          // 0..15
    const int c4 = (tid & 15) << 2;   // 0,4,...,60
    const int x0 = blockIdx.x * 64 + c4;
    const int y0 = blockIdx.y * 64 + r;

    if (!any_near) {
        const float4 z = make_float4(0.0f, 0.0f, 0.0f, 0.0f);
#pragma unroll
        for (int i = 0; i < 4; ++i) {
            *(float4*)(out + (size_t)(y0 + 16 * i) * CANVAS_W + x0) = z;
        }
        return;
    }

    const float xf0 = (float)x0;  // exact: small ints
    const float xf1 = xf0 + 1.0f;
    const float xf2 = xf0 + 2.0f;
    const float xf3 = xf0 + 3.0f;
    const float MAXD = (float)2896.3093757400984;  // fl32(sqrt(8388608))

#pragma unroll
    for (int i = 0; i < 4; ++i) {
        const int y = y0 + 16 * i;
        const float yf = (float)y;
        float m0 = __builtin_inff(), m1 = m0, m2 = m0, m3 = m0;
#pragma unroll
        for (int s = 0; s < NSAMP; ++s) {
            float py = s_y[s];   // LDS broadcast, conflict-free
            float px = s_x[s];
            float dy  = yf - py;
            float dy2 = dy * dy;
            float d0 = xf0 - px;
            float d1 = xf1 - px;
            float d2 = xf2 - px;
            float d3 = xf3 - px;
            m0 = fminf(m0, dy2 + d0 * d0);
            m1 = fminf(m1, dy2 + d1 * d1);
            m2 = fminf(m2, dy2 + d2 * d2);
            m3 = fminf(m3, dy2 + d3 * d3);
        }
        float ms[4] = {m0, m1, m2, m3};
        float vals[4];
#pragma unroll
        for (int j = 0; j < 4; ++j) {
            float v = 0.0f;
            if (ms[j] < 4.0f) {                 // conservative pre-test only
                float dist = sqrtf(ms[j]);      // IEEE-correct (default flags)
                if (dist < 2.0f)                // exact predicate, matches np
                    v = 1.0f - dist / MAXD;     // IEEE div, matches np
            }
            vals[j] = v;
        }
        *(float4*)(out + (size_t)y * CANVAS_W + x0) =
            make_float4(vals[0], vals[1], vals[2], vals[3]);
    }
}

extern "C" void kernel_launch(void* const* d_in, const int* in_sizes, int n_in,
                              void* d_out, int out_size, void* d_ws, size_t ws_size,
                              hipStream_t stream) {
    const float* kp = (const float*)d_in[0];  // [3,2] fp32 (y,x) normalized
    float* out = (float*)d_out;               // [2048,2048] fp32
    dim3 grid(32, 32);                        // 64x64-px tiles
    PathRaster2d_kernel<<<grid, 256, 0, stream>>>(kp, out);
}

// Round 3
// 59.733 us; speedup vs baseline: 1.0342x; 1.0342x over previous
//
#include <hip/hip_runtime.h>
#include <math.h>

// PathRaster2d: quadratic Bezier (3 ctrl pts), 32 uniform-t samples,
// canvas 2048x2048 fp32. out = (dist<2) ? 1 - dist/sqrt(H^2+W^2) : 0.
//
// Numerics mirror the numpy fp32 reference op-for-op (R1: absmax=0):
//  - t_i = float( double(i) * (1.0/31.0) ), t_31 = 1.0  (np.linspace)
//  - basis: (1-t)*(1-t), (2t)*(1-t), t*t
//  - samples: ((b0*k0 + b1*k1) + b2*k2), unfused (fp contract off)
//  - dist2:  dy*dy + dx*dx, unfused; min over samples; IEEE sqrt; IEEE div.
// Any fused/reordered variant risks a 1-ulp flip of the dist<2 predicate
// (unit discontinuity -> absmax 1.0).
//
// R3: revert to the R1 config (32x32-px tiles, 4096 blocks) — best measured
// (59.76 vs 61.78 µs). Timed window is dominated by harness poison fills
// (~45 µs); kernel device time ~1-4 µs, at its 16.8 MB store floor.

#define NSAMP 32
#define CANVAS_W 2048

__global__ __launch_bounds__(256) void PathRaster2d_kernel(
    const float* __restrict__ kp, float* __restrict__ out) {
#pragma clang fp contract(off)
    __shared__ float s_y[NSAMP];
    __shared__ float s_x[NSAMP];

    const int tid = threadIdx.x;

    // Tile = 32x32 pixels. Center for the cull test.
    const float cy = (float)(blockIdx.y * 32) + 15.5f;
    const float cx = (float)(blockIdx.x * 32) + 15.5f;

    int pred = 0;
    if (tid < NSAMP) {
        // np.linspace(0,1,32): step = 1/31 in f64, y_i = i*step, endpoint exact.
        double td = (tid == NSAMP - 1) ? 1.0 : (double)tid * (1.0 / 31.0);
        float t = (float)td;
        float u = 1.0f - t;
        float b0 = u * u;            // comb(2,0) * (1-t)^2
        float b1 = (2.0f * t) * u;   // comb(2,1)*t, then *(1-t)
        float b2 = t * t;            // comb(2,2) * t^2
        float ky0 = kp[0] * 2048.0f, kx0 = kp[1] * 2048.0f;
        float ky1 = kp[2] * 2048.0f, kx1 = kp[3] * 2048.0f;
        float ky2 = kp[4] * 2048.0f, kx2 = kp[5] * 2048.0f;
        // basis @ kp, sequential left-to-right, no fma (contract off).
        float sy = (b0 * ky0 + b1 * ky1) + b2 * ky2;
        float sx = (b0 * kx0 + b1 * kx1) + b2 * kx2;
        s_y[tid] = sy;
        s_x[tid] = sx;
        // Cull: sample within (2 + 15.5*sqrt2 + margin) of tile center.
        // Conservative threshold 640 (25.3^2) absorbs all fp32 slop.
        float dyc = cy - sy;
        float dxc = cx - sx;
        pred = (dyc * dyc + dxc * dxc) < 640.0f;
    }
    int any_near = __syncthreads_or(pred);  // barrier + OR; s_y/s_x visible

    // Thread -> 4 horizontally adjacent pixels inside the 32x32 tile.
    const int r  = tid >> 3;         // row 0..31
    const int c4 = (tid & 7) << 2;   // col 0,4,...,28
    const int y  = blockIdx.y * 32 + r;
    const int x0 = blockIdx.x * 32 + c4;
    float4* outv = (float4*)(out + (size_t)y * CANVAS_W + x0);

    if (!any_near) {
        *outv = make_float4(0.0f, 0.0f, 0.0f, 0.0f);
        return;
    }

    const float yf  = (float)y;
    const float xf0 = (float)x0;        // exact: small ints
    const float xf1 = xf0 + 1.0f;
    const float xf2 = xf0 + 2.0f;
    const float xf3 = xf0 + 3.0f;

    float m0 = __builtin_inff(), m1 = m0, m2 = m0, m3 = m0;
#pragma unroll
    for (int s = 0; s < NSAMP; ++s) {
        float py = s_y[s];   // LDS broadcast, conflict-free
        float px = s_x[s];
        float dy  = yf - py;
        float dy2 = dy * dy;
        float d0 = xf0 - px;
        float d1 = xf1 - px;
        float d2 = xf2 - px;
        float d3 = xf3 - px;
        m0 = fminf(m0, dy2 + d0 * d0);
        m1 = fminf(m1, dy2 + d1 * d1);
        m2 = fminf(m2, dy2 + d2 * d2);
        m3 = fminf(m3, dy2 + d3 * d3);
    }

    const float MAXD = (float)2896.3093757400984;  // fl32(sqrt(8388608))
    float ms[4] = {m0, m1, m2, m3};
    float vals[4];
#pragma unroll
    for (int i = 0; i < 4; ++i) {
        float v = 0.0f;
        if (ms[i] < 4.0f) {                 // conservative pre-test only
            float dist = sqrtf(ms[i]);      // IEEE-correct (default flags)
            if (dist < 2.0f)                // exact predicate, matches np
                v = 1.0f - dist / MAXD;     // IEEE div, matches np
        }
        vals[i] = v;
    }
    *outv = make_float4(vals[0], vals[1], vals[2], vals[3]);
}

extern "C" void kernel_launch(void* const* d_in, const int* in_sizes, int n_in,
                              void* d_out, int out_size, void* d_ws, size_t ws_size,
                              hipStream_t stream) {
    const float* kp = (const float*)d_in[0];  // [3,2] fp32 (y,x) normalized
    float* out = (float*)d_out;               // [2048,2048] fp32
    dim3 grid(64, 64);                        // 32x32-px tiles
    PathRaster2d_kernel<<<grid, 256, 0, stream>>>(kp, out);
}